// Round 7
// baseline (130.253 us; speedup 1.0000x reference)
//
#include <hip/hip_runtime.h>

#define SQd 4096
#define SKVd 4096
#define DDIM 64
#define BK 32                          // keys per tile
#define NG 8                           // key groups (waves) per block
#define NTILES (SKVd / BK)             // 128 tiles per batch
#define NCHUNK (NTILES / 2)            // 64 chunks (64 keys) per batch
#define TPG (NTILES / NG)              // 16 tiles per wave
#define CPG (TPG / 2)                  // 8 chunks per wave
#define KWS_BYTES ((size_t)4 * NTILES * 2048)   // 1 MB fp8 K
#define BROWS 32                       // q-rows per block

typedef float floatx4  __attribute__((ext_vector_type(4)));
typedef float floatx16 __attribute__((ext_vector_type(16)));
typedef int   intx8    __attribute__((ext_vector_type(8)));

// Word-select must be an immediate constant -> template parameter.
template <bool HI>
__device__ inline int pk2(float a, float b, int old) {
    return __builtin_amdgcn_cvt_pk_fp8_f32(a, b, old, HI);
}

__device__ inline intx8 mk8(int4 a, int4 b) {
    intx8 r;
    r[0] = a.x; r[1] = a.y; r[2] = a.z; r[3] = a.w;
    r[4] = b.x; r[5] = b.y; r[6] = b.z; r[7] = b.w;
    return r;
}

// LDS: cross-group combine only (8 key-groups -> 4 slots, 2 rounds).
// 35840 B per block -> 2 blocks/CU co-resident.
struct CombS {
    float Ored[BROWS][4][68];
    float Lred[BROWS][NG];
};

// ---------------- Pre-pass: pack K and V for 32x32x64 f8f6f4 MFMA ----------
// K A-frag  (per 32-key tile, 2048 B): byte(lane*32 + j) =
//     fp8( K[tile*32 + (lane&31)][(lane>>5)*32 + j] ),  j = 0..31
// V B-frag  (per 64-key chunk, per d-half, 2048 B): byte(lane*32 + pt*16 + r) =
//     fp8( V[chunk*64 + pt*32 + (r&3)+8*(r>>2)+4*(lane>>5)][h*32 + (lane&31)] )
// The key permutation matches the 32x32 MFMA C-layout of QK^T, so exp'd P
// bytes feed the PV A-operand directly.
__global__ __launch_bounds__(256)
void prepack_kernel(const float* __restrict__ k, const float* __restrict__ v,
                    char* __restrict__ ws)
{
    __shared__ __align__(16) float Kt[BK][68];
    __shared__ __align__(16) float Vt[BK][68];

    const int blk  = blockIdx.x;          // b*NTILES + tile
    const int b    = blk >> 7;
    const int tile = blk & (NTILES - 1);
    const int tid  = threadIdx.x;

    const size_t base = ((size_t)b * SKVd + tile * BK) * DDIM;
    {
        const int row = tid >> 3, col = (tid & 7) * 8;
        const float4 k0 = *(const float4*)(k + base + (size_t)row * DDIM + col);
        const float4 k1 = *(const float4*)(k + base + (size_t)row * DDIM + col + 4);
        *(float4*)&Kt[row][col] = k0; *(float4*)&Kt[row][col + 4] = k1;
        const float4 v0 = *(const float4*)(v + base + (size_t)row * DDIM + col);
        const float4 v1 = *(const float4*)(v + base + (size_t)row * DDIM + col + 4);
        *(float4*)&Vt[row][col] = v0; *(float4*)&Vt[row][col + 4] = v1;
    }
    __syncthreads();

    const int lane = tid & 63;
    const int q4   = tid >> 6;            // 0..3: sub-slice of the lane's 32 B
    const int l31  = lane & 31;
    const int u    = lane >> 5;

    // K pack: 8 bytes per thread
    {
        const float* s = &Kt[l31][u * 32 + q4 * 8];
        int w0 = pk2<false>(s[0], s[1], 0); w0 = pk2<true>(s[2], s[3], w0);
        int w1 = pk2<false>(s[4], s[5], 0); w1 = pk2<true>(s[6], s[7], w1);
        int2 o2; o2.x = w0; o2.y = w1;
        *(int2*)(ws + (size_t)(b * NTILES + tile) * 2048 + lane * 32 + q4 * 8) = o2;
    }
    // V pack: 8 bytes per thread (h = d-half, rh = reg offset)
    {
        const int h  = q4 >> 1;
        const int rh = (q4 & 1) * 8;
        float p[8];
        #pragma unroll
        for (int i = 0; i < 8; ++i) {
            const int r   = rh + i;
            const int key = (r & 3) + 8 * (r >> 2) + 4 * u;
            p[i] = Vt[key][h * 32 + l31];
        }
        int w0 = pk2<false>(p[0], p[1], 0); w0 = pk2<true>(p[2], p[3], w0);
        int w1 = pk2<false>(p[4], p[5], 0); w1 = pk2<true>(p[6], p[7], w1);
        int2 o2; o2.x = w0; o2.y = w1;
        const size_t voff = KWS_BYTES
            + ((size_t)(b * NCHUNK + (tile >> 1)) * 2 + h) * 2048
            + lane * 32 + (tile & 1) * 16 + rh;
        *(int2*)(ws + voff) = o2;
    }
}

// ---------------- Main kernel ---------------------------------------------
// Wave = 32 q-rows x 512 keys (8 chunks of 64 keys).
// CROSS-CHUNK COMPUTE PIPELINE (the one change vs R4): iteration c issues
// QK(c+1) on the matrix pipe FIRST, then runs exp/pack/l_acc of chunk c on
// the VALU/trans pipes in the MFMA shadow (independent work), then PV(c).
// Rationale: R1-R6 falsified MFMA-count/spill/latency/occupancy/sharing/
// memory-path; the surviving invariant was the serial QK->exp->pack->PV
// chain + wave phase-lockstep => matrix and VALU pipes ping-pong instead of
// overlapping (sum ~24us instead of max ~6us). Manual 2x unroll ping-pongs
// score-state names (no rotation movs). Peak live ~119 VGPR < 128 cap:
// K loads 1 chunk ahead, V same-iteration (covered by exp), K(c+2) issued
// only after both exps free the 32 current-score regs.
__global__ __launch_bounds__(512, 4)
void fattn_kernel(const float* __restrict__ q, const int* __restrict__ isf_p,
                  const char* __restrict__ kws, const char* __restrict__ vws,
                  float* __restrict__ out)
{
    __shared__ CombS C;

    const int tid  = threadIdx.x;
    const int g    = tid >> 6;    // key group 0..7 (512 keys)
    const int lane = tid & 63;
    const int l31  = lane & 31;
    const int u    = lane >> 5;

    const int bidx  = blockIdx.x;       // 0..511
    const int b     = bidx >> 7;        // batch
    const int qbase = (bidx & 127) * BROWS;

    // exp(s) = 2^(s*log2e); constant -4 keeps p' = e^(s-4) within e4m3 range.
    const float scale = 1.44269504088896340736f / (float)(*isf_p);
    const float SINIT = -4.0f * 1.44269504088896340736f;

    // Q B-frag: byte(lane: j) = fp8(Q[qbase + l31][u*32 + j] * scale)
    intx8 qf;
    {
        const float* qp = q + ((size_t)b * SQd + qbase + l31) * DDIM + u * 32;
        #pragma unroll
        for (int d = 0; d < 8; ++d) {
            const float4 a = *(const float4*)(qp + 4 * d);
            int w = pk2<false>(a.x * scale, a.y * scale, 0);
            w     = pk2<true >(a.z * scale, a.w * scale, w);
            qf[d] = w;
        }
    }

    const char* kg = kws + (size_t)(b * NTILES + g * TPG) * 2048 + lane * 32;
    const char* vg = vws + (size_t)(b * NCHUNK + g * CPG) * 4096 + lane * 32;
    const int cph  = bidx & (CPG - 1);   // decorrelate L2 streams across CUs

    floatx16 o0, o1;
    #pragma unroll
    for (int i = 0; i < 16; ++i) { o0[i] = 0.f; o1[i] = 0.f; }
    const floatx16 zc = o0;              // zero C-init (inline-const remat)
    float l_acc = 0.f;

    // K regs (one chunk ahead of compute)
    int4 ka0, ka1, kb0, kb1;
    auto loadK = [&](int c) {
        const size_t off = (size_t)((c + cph) & (CPG - 1)) * 4096;
        ka0 = *(const int4*)(kg + off);        ka1 = *(const int4*)(kg + off + 16);
        kb0 = *(const int4*)(kg + off + 2048); kb1 = *(const int4*)(kg + off + 2064);
    };

    // ---- prologue: QK(0) in flight, K(1) loaded ----
    loadK(0);
    floatx16 sA = __builtin_amdgcn_mfma_scale_f32_32x32x64_f8f6f4(
        mk8(ka0, ka1), qf, zc, 0, 0, 0, 0x7F7F7F7F, 0, 0x7F7F7F7F);
    floatx16 sB = __builtin_amdgcn_mfma_scale_f32_32x32x64_f8f6f4(
        mk8(kb0, kb1), qf, zc, 0, 0, 0, 0x7F7F7F7F, 0, 0x7F7F7F7F);
    loadK(1);
    floatx16 sA2, sB2;

    // One pipelined step: consumes (sc_a, sc_b) = raw QK(c), K regs = K(c+1);
    // produces (sn_a, sn_b) = raw QK(c+1), K regs = K(c+2), o/l updated.
    auto step = [&](floatx16& sc_a, floatx16& sc_b,
                    floatx16& sn_a, floatx16& sn_b, int c) {
        // QK(c+1) issues first -> matrix pipe busy under the VALU work below.
        sn_a = __builtin_amdgcn_mfma_scale_f32_32x32x64_f8f6f4(
            mk8(ka0, ka1), qf, zc, 0, 0, 0, 0x7F7F7F7F, 0, 0x7F7F7F7F);
        sn_b = __builtin_amdgcn_mfma_scale_f32_32x32x64_f8f6f4(
            mk8(kb0, kb1), qf, zc, 0, 0, 0, 0x7F7F7F7F, 0, 0x7F7F7F7F);

        // V(c): same-iteration load, covered by the exp/pack phase below.
        const size_t offc = (size_t)((c + cph) & (CPG - 1)) * 4096;
        const int4 va0 = *(const int4*)(vg + offc);
        const int4 va1 = *(const int4*)(vg + offc + 16);
        const int4 vb0 = *(const int4*)(vg + offc + 2048);
        const int4 vb1 = *(const int4*)(vg + offc + 2064);

        intx8 pa;
        // exp/pack tile A (frees sc_a's 16 regs)
        #pragma unroll
        for (int r = 0; r < 16; ++r) sc_a[r] = __builtin_amdgcn_exp2f(sc_a[r] + SINIT);
        l_acc += ((((sc_a[0] + sc_a[1]) + (sc_a[2] + sc_a[3]))
                 + ((sc_a[4] + sc_a[5]) + (sc_a[6] + sc_a[7])))
                + (((sc_a[8] + sc_a[9]) + (sc_a[10] + sc_a[11]))
                 + ((sc_a[12] + sc_a[13]) + (sc_a[14] + sc_a[15]))));
        #pragma unroll
        for (int d2 = 0; d2 < 4; ++d2) {
            int w = pk2<false>(sc_a[4 * d2], sc_a[4 * d2 + 1], 0);
            pa[d2] = pk2<true>(sc_a[4 * d2 + 2], sc_a[4 * d2 + 3], w);
        }
        // exp/pack tile B (frees sc_b's 16 regs)
        #pragma unroll
        for (int r = 0; r < 16; ++r) sc_b[r] = __builtin_amdgcn_exp2f(sc_b[r] + SINIT);
        l_acc += ((((sc_b[0] + sc_b[1]) + (sc_b[2] + sc_b[3]))
                 + ((sc_b[4] + sc_b[5]) + (sc_b[6] + sc_b[7])))
                + (((sc_b[8] + sc_b[9]) + (sc_b[10] + sc_b[11]))
                 + ((sc_b[12] + sc_b[13]) + (sc_b[14] + sc_b[15]))));
        #pragma unroll
        for (int d2 = 0; d2 < 4; ++d2) {
            int w = pk2<false>(sc_b[4 * d2], sc_b[4 * d2 + 1], 0);
            pa[4 + d2] = pk2<true>(sc_b[4 * d2 + 2], sc_b[4 * d2 + 3], w);
        }

        // K(c+2): issued after both exps freed 32 regs (peak stays ~119).
        loadK(c + 2);

        // PV(c)
        o0 = __builtin_amdgcn_mfma_scale_f32_32x32x64_f8f6f4(
            pa, mk8(va0, va1), o0, 0, 0, 0, 0x7F7F7F7F, 0, 0x7F7F7F7F);
        o1 = __builtin_amdgcn_mfma_scale_f32_32x32x64_f8f6f4(
            pa, mk8(vb0, vb1), o1, 0, 0, 0, 0x7F7F7F7F, 0, 0x7F7F7F7F);
    };

    // CPG = 8 -> 4 double-steps; name ping-pong replaces rotation movs.
    // Last step's QK output (wrapped chunk) is computed and discarded.
    #pragma unroll 1
    for (int c = 0; c < CPG; c += 2) {
        step(sA, sB, sA2, sB2, c);
        step(sA2, sB2, sA, sB, c + 1);
    }

    // Row denominators: lanes l and l+32 hold complementary key halves of
    // qrow = l31.
    l_acc += __shfl_xor(l_acc, 32);
    if (u == 0) C.Lred[l31][g] = l_acc;

    // Cross-group combine: groups 0-3 write slots, barrier, groups 4-7 add.
    // O layout: o_h[r] = O[qrow=(r&3)+8*(r>>2)+4u][d = h*32 + l31]
    if (g < 4) {
        #pragma unroll
        for (int r = 0; r < 16; ++r) {
            const int row = (r & 3) + 8 * (r >> 2) + 4 * u;
            C.Ored[row][g][l31]      = o0[r];
            C.Ored[row][g][32 + l31] = o1[r];
        }
    }
    __syncthreads();
    if (g >= 4) {
        #pragma unroll
        for (int r = 0; r < 16; ++r) {
            const int row = (r & 3) + 8 * (r >> 2) + 4 * u;
            C.Ored[row][g - 4][l31]      += o0[r];
            C.Ored[row][g - 4][32 + l31] += o1[r];
        }
    }
    __syncthreads();

    // Epilogue: out = attn@v + q; 3x { x += 2q; sigmoid; clamp }. Each thread
    // owns 4 consecutive d of one row (512 thr x 4 = 32 rows x 64 d).
    {
        const int row = tid >> 4;
        const int d4  = (tid & 15) * 4;
        float l = 0.0f;
        #pragma unroll
        for (int gg = 0; gg < NG; ++gg) l += C.Lred[row][gg];
        const float rl = 1.0f / l;
        float xs[4] = {0.f, 0.f, 0.f, 0.f};
        #pragma unroll
        for (int s = 0; s < 4; ++s) {
            const float4 t4 = *(const float4*)&C.Ored[row][s][d4];
            xs[0] += t4.x; xs[1] += t4.y; xs[2] += t4.z; xs[3] += t4.w;
        }
        const size_t idx = ((size_t)b * SQd + qbase + row) * DDIM + d4;
        const float4 q4v = *(const float4*)(q + idx);
        const float qs[4] = {q4v.x, q4v.y, q4v.z, q4v.w};
        #pragma unroll
        for (int c = 0; c < 4; ++c) {
            float x = xs[c] * rl + qs[c];
            #pragma unroll
            for (int itc = 0; itc < 3; ++itc) {
                x = x + 2.0f * qs[c];
                x = 1.0f / (1.0f + __expf(-x));
                x = fminf(fmaxf(x, 0.0f), 1.0f);
            }
            xs[c] = x;
        }
        const float4 r4 = {xs[0], xs[1], xs[2], xs[3]};
        *(float4*)(out + idx) = r4;
    }
}

extern "C" void kernel_launch(void* const* d_in, const int* in_sizes, int n_in,
                              void* d_out, int out_size, void* d_ws, size_t ws_size,
                              hipStream_t stream) {
    const float* q = (const float*)d_in[0];
    const float* k = (const float*)d_in[1];
    const float* v = (const float*)d_in[2];
    const int* isf = (const int*)d_in[3];
    float* out = (float*)d_out;
    char* ws = (char*)d_ws;   // Kws: 1 MB, Vws: 1 MB (fp8)

    prepack_kernel<<<dim3(4 * NTILES), dim3(256), 0, stream>>>(k, v, ws);

    const int nblocks = 4 * (SQd / BROWS);  // 512 blocks x 512 threads, 2/CU
    fattn_kernel<<<dim3(nblocks), dim3(512), 0, stream>>>(
        q, isf, ws, ws + KWS_BYTES, out);
}

// Round 8
// 95.506 us; speedup vs baseline: 1.3638x; 1.3638x over previous
//
#include <hip/hip_runtime.h>

#define SQd 4096
#define SKVd 4096
#define DDIM 64
#define BK 32                          // keys per tile
#define NG 8                           // key groups (waves) per block
#define NTILES (SKVd / BK)             // 128 tiles per batch
#define TPG (NTILES / NG)              // 16 tiles per wave
#define TILE_BYTES 2048                // per operand: 2 superfrags x 1024 B
#define KWS_BYTES ((size_t)4 * NTILES * TILE_BYTES)   // 1 MB per operand
#define BROWS 16                       // q-rows per block (ONE 16-row group)

typedef float floatx4 __attribute__((ext_vector_type(4)));

__device__ inline long long mk64(int lo, int hi) {
    int2 t; t.x = lo; t.y = hi;
    return __builtin_bit_cast(long long, t);
}
// Word-select must be an immediate constant -> template parameter.
template <bool HI>
__device__ inline int pk2(float a, float b, int old) {
    return __builtin_amdgcn_cvt_pk_fp8_f32(a, b, old, HI);
}

// LDS: cross-group combine only (8 key-groups -> 4 slots, 2 rounds).
// 17920 B per block -> 4 blocks/CU co-resident.
struct CombS {
    float Ored[BROWS][4][68];
    float Lred[BROWS][NG];
};

// ---------------- Pre-pass: pack K and V into fp8 MFMA superfrags ----------
// (verbatim R0 prepack — verified with this compute structure, absmax 0.0039)
__global__ __launch_bounds__(256)
void prepack_kernel(const float* __restrict__ k, const float* __restrict__ v,
                    char* __restrict__ ws)
{
    __shared__ __align__(16) float Kt[BK][68];
    __shared__ __align__(16) float Vt[BK][68];

    const int blk  = blockIdx.x;          // b*NTILES + tile
    const int b    = blk >> 7;
    const int tile = blk & (NTILES - 1);
    const int tid  = threadIdx.x;

    const size_t base = ((size_t)b * SKVd + tile * BK) * DDIM;
    {
        const int row = tid >> 3, col = (tid & 7) * 8;
        const float4 k0 = *(const float4*)(k + base + (size_t)row * DDIM + col);
        const float4 k1 = *(const float4*)(k + base + (size_t)row * DDIM + col + 4);
        *(float4*)&Kt[row][col] = k0; *(float4*)&Kt[row][col + 4] = k1;
        const float4 v0 = *(const float4*)(v + base + (size_t)row * DDIM + col);
        const float4 v1 = *(const float4*)(v + base + (size_t)row * DDIM + col + 4);
        *(float4*)&Vt[row][col] = v0; *(float4*)&Vt[row][col + 4] = v1;
    }
    __syncthreads();

    const int lane = tid & 63;
    const int l16  = lane & 15;
    const int quad = lane >> 4;
    const int f    = tid >> 6;            // 0,1: K kh; 2,3: V pair

    int w[4];
    size_t off;
    if (f < 2) {
        const float* s0 = &Kt[f * 16 + l16][quad * 8];        // dh0
        const float* s1 = &Kt[f * 16 + l16][32 + quad * 8];   // dh1
        w[0] = pk2<false>(s0[0], s0[1], 0); w[0] = pk2<true>(s0[2], s0[3], w[0]);
        w[1] = pk2<false>(s0[4], s0[5], 0); w[1] = pk2<true>(s0[6], s0[7], w[1]);
        w[2] = pk2<false>(s1[0], s1[1], 0); w[2] = pk2<true>(s1[2], s1[3], w[2]);
        w[3] = pk2<false>(s1[4], s1[5], 0); w[3] = pk2<true>(s1[6], s1[7], w[3]);
        off = ((size_t)(b * NTILES + tile) * 2 + f) * 1024 + lane * 16;
    } else {
        const int p = f - 2;
        float vv[16];
        #pragma unroll
        for (int j2 = 0; j2 < 16; ++j2) {
            const int nb = 2 * p + (j2 >> 3);
            const int j  = j2 & 7;
            vv[j2] = Vt[16 * (j >> 2) + quad * 4 + (j & 3)][nb * 16 + l16];
        }
        #pragma unroll
        for (int i = 0; i < 4; ++i) {
            w[i] = pk2<false>(vv[4 * i], vv[4 * i + 1], 0);
            w[i] = pk2<true>(vv[4 * i + 2], vv[4 * i + 3], w[i]);
        }
        off = (size_t)KWS_BYTES + ((size_t)(b * NTILES + tile) * 2 + p) * 1024 + lane * 16;
    }
    int4 o4; o4.x = w[0]; o4.y = w[1]; o4.z = w[2]; o4.w = w[3];
    *(int4*)(ws + off) = o4;
}

// ---------------- Main kernel ---------------------------------------------
// THE OCCUPANCY EXPERIMENT: R0's verified 16x16x32 fp8 structure, but ONE
// 16-row q-group per wave (half of R0) -> persistent regs ~60, and
// launch_bounds(512,8) caps VGPR at 64 => 8 waves/SIMD (2x every previous
// round's 4). Rationale: R0-R6 falsified MFMA shape, load latency (R4
// prefetch null), L2 volume (R5 halved, null), memory path (R6); clean
// rounds all sat at ~24us with a zero-overlap pipe sum of only ~12.5us ->
// ~half the time neither pipe issues. The per-chunk serial chain
// (MFMA-latency -> exp -> pack -> MFMA) can't be filled by 4 lockstep-ish
// waves; 8 waves/SIMD doubles interleave depth. TLP is the last open axis.
// Block = 512 thr = 8 waves = 8 key-groups over the SAME 16 q-rows.
// Grid 1024 = 4 blocks/CU; LDS 17920 x 4 = 71680 B.
__global__ __launch_bounds__(512, 8)
void fattn_kernel(const float* __restrict__ q, const int* __restrict__ isf_p,
                  const char* __restrict__ kws, const char* __restrict__ vws,
                  float* __restrict__ out)
{
    __shared__ CombS C;

    const int tid  = threadIdx.x;
    const int g    = tid >> 6;    // key group 0..7 (512 keys)
    const int lane = tid & 63;
    const int l16  = lane & 15;
    const int quad = lane >> 4;

    const int bidx  = blockIdx.x;        // 0..1023
    const int b     = bidx >> 8;         // batch (256 blocks per batch)
    const int qbase = (bidx & 255) * BROWS;

    // exp(s) = 2^(s*log2e); constant -4 folded into the MFMA C-init keeps
    // p' = e^(s-4) within e4m3 range.
    const float scale = 1.44269504088896340736f / (float)(*isf_p);
    const float SINIT = -4.0f * 1.44269504088896340736f;

    // Q fp8 B-frags: qf[dh], byte j = fp8(Q[qbase+l16][dh*32+quad*8+j]*scale)
    long long qf0, qf1;
    {
        const float* qp = q + ((size_t)b * SQd + qbase + l16) * DDIM + quad * 8;
        const float4 a0 = *(const float4*)(qp);
        const float4 a1 = *(const float4*)(qp + 4);
        int lo = pk2<false>(a0.x * scale, a0.y * scale, 0);
        lo     = pk2<true>(a0.z * scale, a0.w * scale, lo);
        int hi = pk2<false>(a1.x * scale, a1.y * scale, 0);
        hi     = pk2<true>(a1.z * scale, a1.w * scale, hi);
        qf0 = mk64(lo, hi);
        const float4 b0 = *(const float4*)(qp + 32);
        const float4 b1 = *(const float4*)(qp + 36);
        lo = pk2<false>(b0.x * scale, b0.y * scale, 0);
        lo = pk2<true>(b0.z * scale, b0.w * scale, lo);
        hi = pk2<false>(b1.x * scale, b1.y * scale, 0);
        hi = pk2<true>(b1.z * scale, b1.w * scale, hi);
        qf1 = mk64(lo, hi);
    }

    const char* kg = kws + (size_t)(b * NTILES + g * TPG) * TILE_BYTES + lane * 16;
    const char* vg = vws + (size_t)(b * NTILES + g * TPG) * TILE_BYTES + lane * 16;
    const int phase = bidx & (TPG - 1);   // decorrelate L2 streams across CUs

    floatx4 o[4];
    float l_acc = 0.0f;
    #pragma unroll
    for (int nb = 0; nb < 4; ++nb)
        #pragma unroll
        for (int r = 0; r < 4; ++r) o[nb][r] = 0.0f;
    const floatx4 sinit = {SINIT, SINIT, SINIT, SINIT};

    #pragma unroll 1
    for (int t = 0; t < TPG; ++t) {
        const size_t off = (size_t)((t + phase) & (TPG - 1)) * TILE_BYTES;
        const int4 kc0 = *(const int4*)(kg + off);
        const int4 kc1 = *(const int4*)(kg + off + 1024);
        const int4 vc0 = *(const int4*)(vg + off);
        const int4 vc1 = *(const int4*)(vg + off + 1024);

        const long long k00 = mk64(kc0.x, kc0.y), k01 = mk64(kc0.z, kc0.w);
        const long long k10 = mk64(kc1.x, kc1.y), k11 = mk64(kc1.z, kc1.w);
        const long long v0 = mk64(vc0.x, vc0.y), v1 = mk64(vc0.z, vc0.w);
        const long long v2 = mk64(vc1.x, vc1.y), v3 = mk64(vc1.z, vc1.w);

        floatx4 s0 = sinit, s1 = sinit;  // keys quad*4+r / 16+quad*4+r, qrow l16
        s0 = __builtin_amdgcn_mfma_f32_16x16x32_fp8_fp8(k00, qf0, s0, 0, 0, 0);
        s0 = __builtin_amdgcn_mfma_f32_16x16x32_fp8_fp8(k01, qf1, s0, 0, 0, 0);
        s1 = __builtin_amdgcn_mfma_f32_16x16x32_fp8_fp8(k10, qf0, s1, 0, 0, 0);
        s1 = __builtin_amdgcn_mfma_f32_16x16x32_fp8_fp8(k11, qf1, s1, 0, 0, 0);

        const float p00 = __builtin_amdgcn_exp2f(s0[0]);
        const float p01 = __builtin_amdgcn_exp2f(s0[1]);
        const float p02 = __builtin_amdgcn_exp2f(s0[2]);
        const float p03 = __builtin_amdgcn_exp2f(s0[3]);
        const float p10 = __builtin_amdgcn_exp2f(s1[0]);
        const float p11 = __builtin_amdgcn_exp2f(s1[1]);
        const float p12 = __builtin_amdgcn_exp2f(s1[2]);
        const float p13 = __builtin_amdgcn_exp2f(s1[3]);
        l_acc += (p00 + p01) + (p02 + p03) + (p10 + p11) + (p12 + p13);
        int lo = pk2<false>(p00, p01, 0); lo = pk2<true>(p02, p03, lo);
        int hi = pk2<false>(p10, p11, 0); hi = pk2<true>(p12, p13, hi);
        const long long pf = mk64(lo, hi);   // PV A-frag, sigma byte order
        o[0] = __builtin_amdgcn_mfma_f32_16x16x32_fp8_fp8(pf, v0, o[0], 0, 0, 0);
        o[1] = __builtin_amdgcn_mfma_f32_16x16x32_fp8_fp8(pf, v1, o[1], 0, 0, 0);
        o[2] = __builtin_amdgcn_mfma_f32_16x16x32_fp8_fp8(pf, v2, o[2], 0, 0, 0);
        o[3] = __builtin_amdgcn_mfma_f32_16x16x32_fp8_fp8(pf, v3, o[3], 0, 0, 0);
    }

    // Row denominators: lanes sharing l16 (across quads) hold one row.
    l_acc += __shfl_xor(l_acc, 16);
    l_acc += __shfl_xor(l_acc, 32);
    if (quad == 0) C.Lred[l16][g] = l_acc;

    // Cross-group combine: groups 0-3 write slots, barrier, groups 4-7 add.
    if (g < 4) {
        #pragma unroll
        for (int nb = 0; nb < 4; ++nb)
            #pragma unroll
            for (int r = 0; r < 4; ++r)
                C.Ored[quad * 4 + r][g][nb * 16 + l16] = o[nb][r];
    }
    __syncthreads();
    if (g >= 4) {
        #pragma unroll
        for (int nb = 0; nb < 4; ++nb)
            #pragma unroll
            for (int r = 0; r < 4; ++r)
                C.Ored[quad * 4 + r][g - 4][nb * 16 + l16] += o[nb][r];
    }
    __syncthreads();

    // Epilogue: out = attn@v + q; 3x { x += 2q; sigmoid; clamp }. Each thread
    // owns 2 consecutive d of one row (512 thr x 2 = 16 rows x 64 d).
    {
        const int row = tid >> 5;
        const int d2  = (tid & 31) * 2;
        float l = 0.0f;
        #pragma unroll
        for (int gg = 0; gg < NG; ++gg) l += C.Lred[row][gg];
        const float rl = 1.0f / l;
        float xs[2] = {0.f, 0.f};
        #pragma unroll
        for (int s = 0; s < 4; ++s) {
            xs[0] += C.Ored[row][s][d2];
            xs[1] += C.Ored[row][s][d2 + 1];
        }
        const size_t idx = ((size_t)b * SQd + qbase + row) * DDIM + d2;
        const float2 q2 = *(const float2*)(q + idx);
        const float qs[2] = {q2.x, q2.y};
        #pragma unroll
        for (int c = 0; c < 2; ++c) {
            float x = xs[c] * rl + qs[c];
            #pragma unroll
            for (int itc = 0; itc < 3; ++itc) {
                x = x + 2.0f * qs[c];
                x = 1.0f / (1.0f + __expf(-x));
                x = fminf(fmaxf(x, 0.0f), 1.0f);
            }
            xs[c] = x;
        }
        const float2 r2 = {xs[0], xs[1]};
        *(float2*)(out + idx) = r2;
    }
}

extern "C" void kernel_launch(void* const* d_in, const int* in_sizes, int n_in,
                              void* d_out, int out_size, void* d_ws, size_t ws_size,
                              hipStream_t stream) {
    const float* q = (const float*)d_in[0];
    const float* k = (const float*)d_in[1];
    const float* v = (const float*)d_in[2];
    const int* isf = (const int*)d_in[3];
    float* out = (float*)d_out;
    char* ws = (char*)d_ws;   // Kws: 1 MB, Vws: 1 MB (fp8)

    prepack_kernel<<<dim3(4 * NTILES), dim3(256), 0, stream>>>(k, v, ws);

    const int nblocks = 4 * (SQd / BROWS);  // 1024 blocks x 512 threads, 4/CU
    fattn_kernel<<<dim3(nblocks), dim3(512), 0, stream>>>(
        q, isf, ws, ws + KWS_BYTES, out);
}